// Round 9
// baseline (154.710 us; speedup 1.0000x reference)
//
#include <hip/hip_runtime.h>
#include <math.h>

// cosine similarity of x[256] vs memory[100000][256]; out = distances * one_hot(argmax).
// Memory-bound: 102.4 MB read, 0.4 MB write. HBM floor ~16.5 us @ 6.3 TB/s.
//
// Structure (round 3): 8 lanes per row, 8 rows per wave. Each 8-lane group reads
// one 128B cache line per load instr (full coalescing); per lane: 8 independent
// float4 loads -> 8 outstanding VMEM for latency hiding. Row reduction = 3-step
// __shfl_xor within the 8-lane group (0.75 DS-ops/KB vs 12/KB for the 64-lane
// butterfly of round 2, which measured ~1.8 TB/s effective). Argmax via packed
// u64 (fkey(dist)<<32 | ~row) -> first-max tie-break, no atomics, no ws init.

#define EPSF 1e-8f

constexpr int BLOCK = 256;  // 4 waves
constexpr int LPR   = 8;    // lanes per row
constexpr int RPI   = 8;    // rows per wave-iteration (64/LPR)
constexpr int F4PL  = 8;    // float4 loads per lane per row (64/LPR)

// Monotonic unsigned key for fp32: f1 > f2  <=>  fkey(f1) > fkey(f2)
__device__ __forceinline__ unsigned fkey(float f) {
    unsigned b = __float_as_uint(f);
    return (b & 0x80000000u) ? ~b : (b | 0x80000000u);
}
__device__ __forceinline__ float funkey(unsigned u) {
    unsigned b = (u & 0x80000000u) ? (u & 0x7FFFFFFFu) : ~u;
    return __uint_as_float(b);
}

__global__ __launch_bounds__(BLOCK) void cos_argmax_main(
    const float* __restrict__ x, const float* __restrict__ mem,
    float* __restrict__ out, unsigned long long* __restrict__ part, int nrows)
{
    __shared__ unsigned long long sbest[BLOCK / 64];
    const int lane = threadIdx.x & 63;
    const int wave = threadIdx.x >> 6;
    const int sub  = lane & (LPR - 1);  // position within the 8-lane row group
    const int rsub = lane >> 3;         // which of the 8 rows this lane serves

    // Coalesced zeroing of the output (harness poisons d_out with 0xAA).
    for (int i = blockIdx.x * BLOCK + threadIdx.x; i < nrows; i += gridDim.x * BLOCK)
        out[i] = 0.0f;

    // x fragment: this lane owns float4 indices sub + LPR*k (k=0..7); the 8-lane
    // group collectively covers all 64 float4 of x.
    float4 xv[F4PL];
    float xn = 0.0f;
    #pragma unroll
    for (int k = 0; k < F4PL; ++k) {
        xv[k] = reinterpret_cast<const float4*>(x)[sub + LPR * k];
        xn += xv[k].x * xv[k].x + xv[k].y * xv[k].y + xv[k].z * xv[k].z + xv[k].w * xv[k].w;
    }
    #pragma unroll
    for (int off = 1; off < LPR; off <<= 1) xn += __shfl_xor(xn, off);
    const float xnorm = fmaxf(sqrtf(xn), EPSF);

    unsigned long long best = 0ull;  // smaller than any real packed key
    const int nwaves = gridDim.x * (BLOCK / 64);
    for (int g = blockIdx.x * (BLOCK / 64) + wave; g * RPI < nrows; g += nwaves) {
        const int row = g * RPI + rsub;
        float dot = 0.0f, nrm = 0.0f;
        if (row < nrows) {
            const float4* rp = reinterpret_cast<const float4*>(mem) + (size_t)row * 64 + sub;
            #pragma unroll
            for (int k = 0; k < F4PL; ++k) {   // 8 independent loads, issued back-to-back
                const float4 mv = rp[LPR * k];
                dot += mv.x * xv[k].x + mv.y * xv[k].y + mv.z * xv[k].z + mv.w * xv[k].w;
                nrm += mv.x * mv.x + mv.y * mv.y + mv.z * mv.z + mv.w * mv.w;
            }
        }
        #pragma unroll
        for (int off = 1; off < LPR; off <<= 1) {  // 3-step reduce within row group
            dot += __shfl_xor(dot, off);
            nrm += __shfl_xor(nrm, off);
        }
        if (row < nrows) {
            const float dist = dot / (fmaxf(sqrtf(nrm), EPSF) * xnorm);
            const unsigned long long p = ((unsigned long long)fkey(dist) << 32)
                                       | (unsigned long long)(0xFFFFFFFFu - (unsigned)row);
            best = (p > best) ? p : best;
        }
    }

    // Once per wave: 64-lane u64 butterfly for the wave's best.
    #pragma unroll
    for (int off = 1; off < 64; off <<= 1) {
        const unsigned long long o = __shfl_xor(best, off);
        best = (o > best) ? o : best;
    }
    if (lane == 0) sbest[wave] = best;
    __syncthreads();
    if (threadIdx.x == 0) {
        unsigned long long b = sbest[0];
        #pragma unroll
        for (int w = 1; w < BLOCK / 64; ++w) b = (sbest[w] > b) ? sbest[w] : b;
        part[blockIdx.x] = b;
    }
}

__global__ __launch_bounds__(BLOCK) void cos_argmax_final(
    const unsigned long long* __restrict__ part, float* __restrict__ out, int nparts)
{
    __shared__ unsigned long long sred[BLOCK];
    unsigned long long best = 0ull;
    for (int i = threadIdx.x; i < nparts; i += BLOCK) {
        const unsigned long long p = part[i];
        best = (p > best) ? p : best;
    }
    sred[threadIdx.x] = best;
    __syncthreads();
    for (int s = BLOCK / 2; s > 0; s >>= 1) {
        if (threadIdx.x < s) {
            const unsigned long long o = sred[threadIdx.x + s];
            if (o > sred[threadIdx.x]) sred[threadIdx.x] = o;
        }
        __syncthreads();
    }
    if (threadIdx.x == 0) {
        const unsigned long long b = sred[0];
        const unsigned idx = 0xFFFFFFFFu - (unsigned)(b & 0xFFFFFFFFull);
        out[idx] = funkey((unsigned)(b >> 32));
    }
}

extern "C" void kernel_launch(void* const* d_in, const int* in_sizes, int n_in,
                              void* d_out, int out_size, void* d_ws, size_t ws_size,
                              hipStream_t stream) {
    const float* x   = (const float*)d_in[0];
    const float* mem = (const float*)d_in[1];
    float* out       = (float*)d_out;
    const int nrows  = in_sizes[1] / 256;                 // 100000
    unsigned long long* part = (unsigned long long*)d_ws; // nblk * 8 B scratch

    // One 8-row strip per wave: nblk = ceil(nrows / (RPI * waves_per_block))
    const int nblk = (nrows + RPI * (BLOCK / 64) - 1) / (RPI * (BLOCK / 64));  // 3125

    cos_argmax_main<<<nblk, BLOCK, 0, stream>>>(x, mem, out, part, nrows);
    cos_argmax_final<<<1, BLOCK, 0, stream>>>(part, out, nblk);
}